// Round 4
// baseline (10141.795 us; speedup 1.0000x reference)
//
#include <hip/hip_runtime.h>

#define N96 884736
#define N48 110592
#define N24 13824
#define N12 1728
#define N6  216

static __device__ __forceinline__ float lrelu_f(float x){ return x >= 0.f ? x : 0.2f*x; }
static __device__ __forceinline__ int clampi(int v,int lo,int hi){ return v<lo?lo:(v>hi?hi:v); }

// ---------------- concat source+target -> X (2,96^3) ----------------
__global__ void concat_k(const float* __restrict__ a, const float* __restrict__ b, float* __restrict__ X){
    int t = blockIdx.x*blockDim.x + threadIdx.x;
    if (t < N96){ X[t] = a[t]; X[N96 + t] = b[t]; }
}

// ---------------- shared conv body: 3^3 conv, stride S, SAME ----------------
template<int OCPB, int S, bool RELU>
static __device__ __forceinline__ void conv_body(
    const float* __restrict__ in1, int C1,
    const float* __restrict__ in2, int C2,
    const float* __restrict__ w, const float* __restrict__ b,
    float* __restrict__ out, int ID, int OD,
    long out_cstride, int out_vmul, int t, int oc0)
{
    int i2 = t % OD; int r = t / OD; int i1 = r % OD; int i0 = r / OD;

    float acc[OCPB];
    #pragma unroll
    for (int j=0; j<OCPB; ++j) acc[j] = b[oc0+j];

    int zz[3], yy[3], xx[3]; bool zv[3], yv[3], xv[3];
    #pragma unroll
    for (int k=0; k<3; ++k){
        int a0 = (S==2) ? (2*i0+k) : (i0+k-1);
        int a1 = (S==2) ? (2*i1+k) : (i1+k-1);
        int a2 = (S==2) ? (2*i2+k) : (i2+k-1);
        zz[k]=a0; zv[k]=(a0>=0)&&(a0<ID);
        yy[k]=a1; yv[k]=(a1>=0)&&(a1<ID);
        xx[k]=a2; xv[k]=(a2>=0)&&(a2<ID);
    }
    const int C = C1 + C2;
    const int ID2 = ID*ID;
    const long ID3 = (long)ID2*ID;

    for (int s=0; s<2; ++s){
        const float* ip = s ? in2 : in1;
        int Cs  = s ? C2 : C1;
        int icb = s ? C1 : 0;
        if (Cs == 0) continue;
        #pragma unroll 2
        for (int ic=0; ic<Cs; ++ic){
            const float* ipb = ip + (long)ic*ID3;
            float v[27];
            #pragma unroll
            for (int kd=0; kd<3; ++kd)
            #pragma unroll
            for (int kh=0; kh<3; ++kh)
            #pragma unroll
            for (int kw=0; kw<3; ++kw){
                bool ok = zv[kd] && yv[kh] && xv[kw];
                v[kd*9+kh*3+kw] = ok ? ipb[(long)zz[kd]*ID2 + yy[kh]*ID + xx[kw]] : 0.f;
            }
            const float* wbase = w + ((long)oc0*C + (icb+ic))*27;
            #pragma unroll
            for (int j=0; j<OCPB; ++j){
                const float* wo = wbase + (long)j*C*27;
                float sacc = 0.f;
                #pragma unroll
                for (int k=0; k<27; ++k) sacc += wo[k]*v[k];
                acc[j] += sacc;
            }
        }
    }
    #pragma unroll
    for (int j=0; j<OCPB; ++j){
        float o = RELU ? lrelu_f(acc[j]) : acc[j];
        out[(long)(oc0+j)*out_cstride + (long)t*out_vmul] = o;
    }
}

// single-path conv
template<int OCPB, int S, bool RELU>
__global__ void conv3d_k(const float* __restrict__ in1, int C1,
                         const float* __restrict__ in2, int C2,
                         const float* __restrict__ w, const float* __restrict__ b,
                         float* __restrict__ out, int ID, int OD,
                         long out_cstride, int out_vmul)
{
    int nvox = OD*OD*OD;
    int t = blockIdx.x*blockDim.x + threadIdx.x;
    if (t >= nvox) return;
    conv_body<OCPB,S,RELU>(in1,C1,in2,C2,w,b,out,ID,OD,out_cstride,out_vmul,t,blockIdx.y*OCPB);
}

// dual-path conv: blockIdx.z selects {A,B} parameter set (cnn path / enc path fused)
template<int OCPB, int S, bool RELU>
__global__ void conv3d_dual_k(const float* __restrict__ in1A, const float* __restrict__ in2A,
                              const float* __restrict__ in1B, const float* __restrict__ in2B,
                              int C1, int C2,
                              const float* __restrict__ wA, const float* __restrict__ bA,
                              const float* __restrict__ wB, const float* __restrict__ bB,
                              float* __restrict__ outA, float* __restrict__ outB,
                              int ID, int OD)
{
    int nvox = OD*OD*OD;
    int t = blockIdx.x*blockDim.x + threadIdx.x;
    if (t >= nvox) return;
    long nv = nvox;
    if (blockIdx.z == 0)
        conv_body<OCPB,S,RELU>(in1A,C1,in2A,C2,wA,bA,outA,ID,OD,nv,1,t,blockIdx.y*OCPB);
    else
        conv_body<OCPB,S,RELU>(in1B,C1,in2B,C2,wB,bB,outB,ID,OD,nv,1,t,blockIdx.y*OCPB);
}

// ---------------- transposed conv 3^3 s=2 SAME + lrelu, parity-specialized ----------------
template<int OCPB>
__global__ void convt_cell_k(const float* __restrict__ in, int I,
                             const float* __restrict__ w, const float* __restrict__ b,
                             float* __restrict__ out, int ID)
{
    const int OD = 2*ID;
    int ncell = ID*ID*ID;
    int t = blockIdx.x*blockDim.x + threadIdx.x;
    if (t >= ncell) return;
    int oc0 = blockIdx.y*OCPB;
    int a2 = t % ID; int r = t/ID; int a1 = r % ID; int a0 = r/ID;

    float acc[8*OCPB];
    #pragma unroll
    for (int j=0;j<OCPB;++j){
        float bb = b[oc0+j];
        #pragma unroll
        for (int p=0;p<8;++p) acc[j*8+p] = bb;
    }

    const int ID2=ID*ID;
    const long ID3=(long)ID2*ID;

    #pragma unroll 2
    for (int ic=0; ic<I; ++ic){
        const float* ip = in + (long)ic*ID3;
        float iv[2][2][2];
        #pragma unroll
        for (int dz=0;dz<2;++dz)
        #pragma unroll
        for (int dy=0;dy<2;++dy)
        #pragma unroll
        for (int dx=0;dx<2;++dx){
            int z = a0-1+dz, y = a1-1+dy, x = a2-1+dx;
            bool ok = (z>=0)&&(y>=0)&&(x>=0);
            iv[dz][dy][dx] = ok ? ip[(long)z*ID2 + y*ID + x] : 0.f;
        }
        #pragma unroll
        for (int j=0;j<OCPB;++j){
            const float* wp = w + ((long)(oc0+j)*I + ic)*27;
            #pragma unroll
            for (int p0=0;p0<2;++p0)
            #pragma unroll
            for (int p1=0;p1<2;++p1)
            #pragma unroll
            for (int p2=0;p2<2;++p2){
                float s = 0.f;
                #pragma unroll
                for (int q0=0;q0<(p0?1:2);++q0){
                    int k0 = p0?1:(q0?2:0); int d0 = p0?1:q0;
                    #pragma unroll
                    for (int q1=0;q1<(p1?1:2);++q1){
                        int k1 = p1?1:(q1?2:0); int d1 = p1?1:q1;
                        #pragma unroll
                        for (int q2=0;q2<(p2?1:2);++q2){
                            int k2 = p2?1:(q2?2:0); int d2 = p2?1:q2;
                            s += wp[k0*9+k1*3+k2] * iv[d0][d1][d2];
                        }
                    }
                }
                acc[j*8 + p0*4+p1*2+p2] += s;
            }
        }
    }
    const int OD2 = OD*OD;
    const long OD3 = (long)OD2*OD;
    #pragma unroll
    for (int j=0;j<OCPB;++j)
    #pragma unroll
    for (int p0=0;p0<2;++p0)
    #pragma unroll
    for (int p1=0;p1<2;++p1)
    #pragma unroll
    for (int p2=0;p2<2;++p2){
        out[(long)(oc0+j)*OD3 + (long)(2*a0+p0)*OD2 + (2*a1+p1)*OD + (2*a2+p2)]
            = lrelu_f(acc[j*8 + p0*4+p1*2+p2]);
    }
}

// ---------------- affine head ----------------
static __device__ void mat4mul(const double* A, const double* B, double* C){
    for (int i=0;i<4;++i) for (int j=0;j<4;++j){
        double s=0; for (int k=0;k<4;++k) s += A[i*4+k]*B[k*4+j];
        C[i*4+j]=s;
    }
}

__global__ void affine_k(const float* __restrict__ c4, float* __restrict__ aff_out, float* __restrict__ mats){
    __shared__ float p[7];
    int t = threadIdx.x;
    if (t < 7){
        float s = 0.f;
        for (int i=0;i<N6;++i) s += c4[t*N6 + i];
        p[t] = s / (float)N6;
        aff_out[t] = p[t];
    }
    __syncthreads();
    if (t == 0){
        double M[16];
        for (int i=0;i<16;++i) M[i]=0.0;
        M[0*4+3]=p[0]; M[1*4+3]=p[1]; M[2*4+3]=p[2];
        M[0*4+1]= p[3]; M[1*4+0]=-p[3];
        M[0*4+2]= p[4]; M[2*4+0]=-p[4];
        M[1*4+2]= p[5]; M[2*4+1]=-p[5];
        M[0*4+0]+=p[6]; M[1*4+1]+=p[6]; M[2*4+2]+=p[6];
        double nrm=0.0;
        for (int i=0;i<4;++i){
            double s=0; for (int j=0;j<4;++j) s += fabs(M[i*4+j]);
            if (s>nrm) nrm=s;
        }
        int jj=0;
        while (nrm > 0.25 && jj < 40){ nrm *= 0.5; ++jj; }
        double sc = 1.0; for (int q=0;q<jj;++q) sc *= 0.5;
        double Ms[16]; for (int i=0;i<16;++i) Ms[i]=M[i]*sc;
        double E[16], T[16], Tn[16];
        for (int i=0;i<16;++i){ E[i] = (i%5==0)?1.0:0.0; T[i]=E[i]; }
        for (int k=1;k<=18;++k){
            mat4mul(T, Ms, Tn);
            double inv = 1.0/(double)k;
            for (int i=0;i<16;++i){ T[i]=Tn[i]*inv; E[i]+=T[i]; }
        }
        for (int q=0;q<jj;++q){ mat4mul(E,E,Tn); for (int i=0;i<16;++i) E[i]=Tn[i]; }
        const double tsh = -48.0;
        for (int i=0;i<3;++i){
            for (int j=0;j<3;++j) mats[i*3+j] = (float)E[i*4+j];
            double rs = (E[i*4+0] - (i==0?1.0:0.0))
                      + (E[i*4+1] - (i==1?1.0:0.0))
                      + (E[i*4+2] - (i==2?1.0:0.0));
            mats[9+i] = (float)(E[i*4+3] + rs*tsh);
        }
    }
}

// ---------------- trilinear helpers ----------------
static __device__ __forceinline__ void trilerp3(const float* __restrict__ f, int D,
                                                float c0, float c1, float c2, float out3[3]){
    float f0=floorf(c0), f1=floorf(c1), f2=floorf(c2);
    float w0=c0-f0, w1=c1-f1, w2=c2-f2;
    int a0=(int)f0, a1=(int)f1, a2=(int)f2;
    int i0s[2]={clampi(a0,0,D-1), clampi(a0+1,0,D-1)};
    int i1s[2]={clampi(a1,0,D-1), clampi(a1+1,0,D-1)};
    int i2s[2]={clampi(a2,0,D-1), clampi(a2+1,0,D-1)};
    float w0s[2]={1.f-w0,w0}, w1s[2]={1.f-w1,w1}, w2s[2]={1.f-w2,w2};
    out3[0]=out3[1]=out3[2]=0.f;
    #pragma unroll
    for (int dx=0;dx<2;++dx)
    #pragma unroll
    for (int dy=0;dy<2;++dy)
    #pragma unroll
    for (int dz=0;dz<2;++dz){
        float wg = w0s[dx]*w1s[dy]*w2s[dz];
        const float* pp = f + ((i0s[dx]*D + i1s[dy])*D + i2s[dz])*3;
        out3[0]+=wg*pp[0]; out3[1]+=wg*pp[1]; out3[2]+=wg*pp[2];
    }
}

static __device__ __forceinline__ float trilerp1(const float* __restrict__ f, int D,
                                                 float c0, float c1, float c2){
    float f0=floorf(c0), f1=floorf(c1), f2=floorf(c2);
    float w0=c0-f0, w1=c1-f1, w2=c2-f2;
    int a0=(int)f0, a1=(int)f1, a2=(int)f2;
    int i0s[2]={clampi(a0,0,D-1), clampi(a0+1,0,D-1)};
    int i1s[2]={clampi(a1,0,D-1), clampi(a1+1,0,D-1)};
    int i2s[2]={clampi(a2,0,D-1), clampi(a2+1,0,D-1)};
    float w0s[2]={1.f-w0,w0}, w1s[2]={1.f-w1,w1}, w2s[2]={1.f-w2,w2};
    float s=0.f;
    #pragma unroll
    for (int dx=0;dx<2;++dx)
    #pragma unroll
    for (int dy=0;dy<2;++dy)
    #pragma unroll
    for (int dz=0;dz<2;++dz){
        float wg = w0s[dx]*w1s[dy]*w2s[dz];
        s += wg * f[(i0s[dx]*D + i1s[dy])*D + i2s[dz]];
    }
    return s;
}

// ---------------- vel -> d0 ----------------
__global__ void resize_small_k(const float* __restrict__ vel, float* __restrict__ dA){
    int t = blockIdx.x*blockDim.x + threadIdx.x;
    if (t >= N48) return;
    int i2 = t % 48; int r = t / 48; int i1 = r % 48; int i0 = r / 48;
    const float s = 95.f/47.f;
    float o[3];
    trilerp3(vel, 96, i0*s, i1*s, i2*s, o);
    const float k = 0.5f/256.f;
    dA[t*3+0]=o[0]*k; dA[t*3+1]=o[1]*k; dA[t*3+2]=o[2]*k;
}

// ---------------- squaring iteration ----------------
__global__ void sq_k(const float* __restrict__ din, float* __restrict__ dout){
    int t = blockIdx.x*blockDim.x + threadIdx.x;
    if (t >= N48) return;
    int i2 = t % 48; int r = t / 48; int i1 = r % 48; int i0 = r / 48;
    float d0=din[t*3+0], d1=din[t*3+1], d2=din[t*3+2];
    float s[3];
    trilerp3(din, 48, (float)i0+d0, (float)i1+d1, (float)i2+d2, s);
    dout[t*3+0]=d0+s[0]; dout[t*3+1]=d1+s[1]; dout[t*3+2]=d2+s[2];
}

// ---------------- fused grid upsample + affine + final pull ----------------
__global__ void grid_pull_k(const float* __restrict__ dfin, const float* __restrict__ src,
                            const float* __restrict__ mats, float* __restrict__ out){
    int t = blockIdx.x*blockDim.x + threadIdx.x;
    if (t >= N96) return;
    int i2 = t % 96; int r = t / 96; int i1 = r % 96; int i0 = r / 96;
    const float sc = 47.f/95.f;
    float c0=i0*sc, c1=i1*sc, c2=i2*sc;
    float s[3];
    trilerp3(dfin, 48, c0, c1, c2, s);
    float g0 = 2.f*(c0+s[0]), g1 = 2.f*(c1+s[1]), g2 = 2.f*(c2+s[2]);
    float L00=mats[0],L01=mats[1],L02=mats[2],L10=mats[3],L11=mats[4],L12=mats[5],
          L20=mats[6],L21=mats[7],L22=mats[8],o0=mats[9],o1=mats[10],o2=mats[11];
    float gg0 = L00*g0 + L01*g1 + L02*g2 + o0;
    float gg1 = L10*g0 + L11*g1 + L12*g2 + o1;
    float gg2 = L20*g0 + L21*g1 + L22*g2 + o2;
    bool inb = (gg0>=0.f)&&(gg0<=95.f)&&(gg1>=0.f)&&(gg1<=95.f)&&(gg2>=0.f)&&(gg2<=95.f);
    float val = trilerp1(src, 96, gg0, gg1, gg2);
    out[t] = inb ? val : 0.f;
}

// ---------------- host side ----------------
extern "C" void kernel_launch(void* const* d_in, const int* in_sizes, int n_in,
                              void* d_out, int out_size, void* d_ws, size_t ws_size,
                              hipStream_t stream) {
    const float* src = (const float*)d_in[0];
    const float* tgt = (const float*)d_in[1];
    const float *cw[5], *cb[5], *ew[4], *eb[4], *uw[4], *ub[4], *dw[4], *db[4];
    for (int i=0;i<5;++i){ cw[i]=(const float*)d_in[2+2*i]; cb[i]=(const float*)d_in[3+2*i]; }
    for (int i=0;i<4;++i){ ew[i]=(const float*)d_in[12+2*i]; eb[i]=(const float*)d_in[13+2*i]; }
    for (int i=0;i<4;++i){ uw[i]=(const float*)d_in[20+2*i]; ub[i]=(const float*)d_in[21+2*i]; }
    for (int i=0;i<4;++i){ dw[i]=(const float*)d_in[28+2*i]; db[i]=(const float*)d_in[29+2*i]; }
    const float* fw = (const float*)d_in[36];
    const float* fb = (const float*)d_in[37];

    float* ws = (float*)d_ws;
    const long OFF_X  = 0;
    const long OFF_E0 = OFF_X  + 2L*N96;
    const long OFF_E1 = OFF_E0 + 16L*N48;
    const long OFF_E2 = OFF_E1 + 32L*N24;
    const long OFF_E3 = OFF_E2 + 32L*N12;
    const long OFF_B1 = OFF_E3 + 32L*N6;
    const long OFF_B2 = OFF_B1 + 16L*N96;
    const long OFF_DA = OFF_B2 + 16L*N96;
    const long OFF_DB = OFF_DA + 3L*N48;
    const long OFF_MT = OFF_DB + 3L*N48;
    const long WS_TOT = OFF_MT + 16;
    if (ws_size < (size_t)WS_TOT*4) return;

    float* X  = ws + OFF_X;
    float* E0 = ws + OFF_E0;
    float* E1 = ws + OFF_E1;
    float* E2 = ws + OFF_E2;
    float* E3 = ws + OFF_E3;
    float* B1 = ws + OFF_B1;
    float* B2 = ws + OFF_B2;
    float* DA = ws + OFF_DA;
    float* DB = ws + OFF_DB;
    float* MT = ws + OFF_MT;

    float* out_def = (float*)d_out;
    float* out_vel = out_def + N96;
    float* out_aff = out_vel + 3L*N96;

    auto gsz = [](int n, int b){ return (n + b - 1)/b; };

    concat_k<<<gsz(N96,256), 256, 0, stream>>>(src, tgt, X);

    // fused cnn/enc downsample cascade: z=0 -> cnn path (B1/B2 ping-pong), z=1 -> enc path (E0..E3)
    conv3d_dual_k< 8,2,true><<<dim3(gsz(N48,256), 2,2), 256, 0, stream>>>(src,tgt, src,tgt, 1,1, cw[0],cb[0], ew[0],eb[0], B1,E0, 96,48);
    conv3d_dual_k< 4,2,true><<<dim3(gsz(N24,256), 8,2), 256, 0, stream>>>(B1,nullptr, E0,nullptr, 16,0, cw[1],cb[1], ew[1],eb[1], B2,E1, 48,24);
    conv3d_dual_k< 2,2,true><<<dim3(gsz(N12, 64),16,2),  64, 0, stream>>>(B2,nullptr, E1,nullptr, 32,0, cw[2],cb[2], ew[2],eb[2], B1,E2, 24,12);
    conv3d_dual_k< 1,2,true><<<dim3(gsz(N6 , 64),32,2),  64, 0, stream>>>(B1,nullptr, E2,nullptr, 32,0, cw[3],cb[3], ew[3],eb[3], B2,E3, 12, 6);
    conv3d_k< 1,1,false><<<dim3(gsz(N6 , 64), 7), 64, 0, stream>>>(B2,32, nullptr, 0, cw[4], cb[4], B1, 6, 6, N6, 1);
    affine_k<<<1, 64, 0, stream>>>(B1, out_aff, MT);

    // decoder
    convt_cell_k<1><<<dim3(gsz(N6 , 64),32), 64, 0, stream>>>(E3, 32, uw[0], ub[0], B2, 6);
    conv3d_k< 2,1,true><<<dim3(gsz(N12, 64),16), 64, 0, stream>>>(B2,32, E2,32, dw[0], db[0], B1, 12, 12, N12, 1);
    convt_cell_k<4><<<dim3(gsz(N12, 64), 8), 64, 0, stream>>>(B1, 32, uw[1], ub[1], B2, 12);
    conv3d_k< 4,1,true><<<dim3(gsz(N24,256), 8), 256, 0, stream>>>(B2,32, E1,32, dw[1], db[1], B1, 24, 24, N24, 1);
    convt_cell_k<4><<<dim3(gsz(N24,256), 8), 256, 0, stream>>>(B1, 32, uw[2], ub[2], B2, 24);
    conv3d_k< 8,1,true><<<dim3(gsz(N48,256), 4), 256, 0, stream>>>(B2,32, E0,16, dw[2], db[2], B1, 48, 48, N48, 1);
    convt_cell_k<4><<<dim3(gsz(N48,256), 4), 256, 0, stream>>>(B1, 32, uw[3], ub[3], B2, 48);
    conv3d_k< 8,1,true><<<dim3(gsz(N96,256), 2), 256, 0, stream>>>(B2,16, X, 2, dw[3], db[3], B1, 96, 96, N96, 1);

    // final conv -> vel (channel-last into d_out)
    conv3d_k< 3,1,false><<<dim3(gsz(N96,256), 1), 256, 0, stream>>>(B1,16, nullptr, 0, fw, fb, out_vel, 96, 96, 1, 3);

    // velocity integration
    resize_small_k<<<gsz(N48,256), 256, 0, stream>>>(out_vel, DA);
    float* da = DA; float* dbuf = DB;
    for (int it=0; it<8; ++it){
        sq_k<<<gsz(N48,256), 256, 0, stream>>>(da, dbuf);
        float* tmp = da; da = dbuf; dbuf = tmp;
    }

    // grid upsample + affine + final warp
    grid_pull_k<<<gsz(N96,256), 256, 0, stream>>>(da, src, MT, out_def);
}

// Round 5
// 1421.472 us; speedup vs baseline: 7.1347x; 7.1347x over previous
//
#include <hip/hip_runtime.h>

#define N96 884736
#define N48 110592
#define N24 13824
#define N12 1728
#define N6  216

static __device__ __forceinline__ float lrelu_f(float x){ return x >= 0.f ? x : 0.2f*x; }
static __device__ __forceinline__ int clampi(int v,int lo,int hi){ return v<lo?lo:(v>hi?hi:v); }

// ---------------- concat source+target -> X (2,96^3) ----------------
__global__ void concat_k(const float* __restrict__ a, const float* __restrict__ b, float* __restrict__ X){
    int t = blockIdx.x*blockDim.x + threadIdx.x;
    if (t < N96){ X[t] = a[t]; X[N96 + t] = b[t]; }
}

// ---------------- shared conv body: 3^3 conv, stride S, SAME ----------------
// NOTE: no unroll on the ic loop — R4's unroll-2 doubled the live v[27] set,
// spilled to scratch (16 GB/dispatch HBM traffic). Keep one v[27] live.
template<int OCPB, int S, bool RELU>
static __device__ __forceinline__ void conv_body(
    const float* __restrict__ in1, int C1,
    const float* __restrict__ in2, int C2,
    const float* __restrict__ w, const float* __restrict__ b,
    float* __restrict__ out, int ID, int OD,
    long out_cstride, int out_vmul, int t, int oc0)
{
    int i2 = t % OD; int r = t / OD; int i1 = r % OD; int i0 = r / OD;

    float acc[OCPB];
    #pragma unroll
    for (int j=0; j<OCPB; ++j) acc[j] = b[oc0+j];

    int zz[3], yy[3], xx[3]; bool zv[3], yv[3], xv[3];
    #pragma unroll
    for (int k=0; k<3; ++k){
        int a0 = (S==2) ? (2*i0+k) : (i0+k-1);
        int a1 = (S==2) ? (2*i1+k) : (i1+k-1);
        int a2 = (S==2) ? (2*i2+k) : (i2+k-1);
        zz[k]=a0; zv[k]=(a0>=0)&&(a0<ID);
        yy[k]=a1; yv[k]=(a1>=0)&&(a1<ID);
        xx[k]=a2; xv[k]=(a2>=0)&&(a2<ID);
    }
    const int C = C1 + C2;
    const int ID2 = ID*ID;
    const long ID3 = (long)ID2*ID;

    for (int s=0; s<2; ++s){
        const float* ip = s ? in2 : in1;
        int Cs  = s ? C2 : C1;
        int icb = s ? C1 : 0;
        if (Cs == 0) continue;
        for (int ic=0; ic<Cs; ++ic){
            const float* ipb = ip + (long)ic*ID3;
            float v[27];
            #pragma unroll
            for (int kd=0; kd<3; ++kd)
            #pragma unroll
            for (int kh=0; kh<3; ++kh)
            #pragma unroll
            for (int kw=0; kw<3; ++kw){
                bool ok = zv[kd] && yv[kh] && xv[kw];
                v[kd*9+kh*3+kw] = ok ? ipb[(long)zz[kd]*ID2 + yy[kh]*ID + xx[kw]] : 0.f;
            }
            const float* wbase = w + ((long)oc0*C + (icb+ic))*27;
            #pragma unroll
            for (int j=0; j<OCPB; ++j){
                const float* wo = wbase + (long)j*C*27;
                float sacc = 0.f;
                #pragma unroll
                for (int k=0; k<27; ++k) sacc += wo[k]*v[k];
                acc[j] += sacc;
            }
        }
    }
    #pragma unroll
    for (int j=0; j<OCPB; ++j){
        float o = RELU ? lrelu_f(acc[j]) : acc[j];
        out[(long)(oc0+j)*out_cstride + (long)t*out_vmul] = o;
    }
}

// single-path conv
template<int OCPB, int S, bool RELU>
__global__ void conv3d_k(const float* __restrict__ in1, int C1,
                         const float* __restrict__ in2, int C2,
                         const float* __restrict__ w, const float* __restrict__ b,
                         float* __restrict__ out, int ID, int OD,
                         long out_cstride, int out_vmul)
{
    int nvox = OD*OD*OD;
    int t = blockIdx.x*blockDim.x + threadIdx.x;
    if (t >= nvox) return;
    conv_body<OCPB,S,RELU>(in1,C1,in2,C2,w,b,out,ID,OD,out_cstride,out_vmul,t,blockIdx.y*OCPB);
}

// dual-path conv: blockIdx.z selects {A,B} parameter set (cnn path / enc path fused)
template<int OCPB, int S, bool RELU>
__global__ void conv3d_dual_k(const float* __restrict__ in1A, const float* __restrict__ in2A,
                              const float* __restrict__ in1B, const float* __restrict__ in2B,
                              int C1, int C2,
                              const float* __restrict__ wA, const float* __restrict__ bA,
                              const float* __restrict__ wB, const float* __restrict__ bB,
                              float* __restrict__ outA, float* __restrict__ outB,
                              int ID, int OD)
{
    int nvox = OD*OD*OD;
    int t = blockIdx.x*blockDim.x + threadIdx.x;
    if (t >= nvox) return;
    long nv = nvox;
    if (blockIdx.z == 0)
        conv_body<OCPB,S,RELU>(in1A,C1,in2A,C2,wA,bA,outA,ID,OD,nv,1,t,blockIdx.y*OCPB);
    else
        conv_body<OCPB,S,RELU>(in1B,C1,in2B,C2,wB,bB,outB,ID,OD,nv,1,t,blockIdx.y*OCPB);
}

// ---------------- transposed conv 3^3 s=2 SAME + lrelu, parity-specialized ----------------
template<int OCPB>
__global__ void convt_cell_k(const float* __restrict__ in, int I,
                             const float* __restrict__ w, const float* __restrict__ b,
                             float* __restrict__ out, int ID)
{
    const int OD = 2*ID;
    int ncell = ID*ID*ID;
    int t = blockIdx.x*blockDim.x + threadIdx.x;
    if (t >= ncell) return;
    int oc0 = blockIdx.y*OCPB;
    int a2 = t % ID; int r = t/ID; int a1 = r % ID; int a0 = r/ID;

    float acc[8*OCPB];
    #pragma unroll
    for (int j=0;j<OCPB;++j){
        float bb = b[oc0+j];
        #pragma unroll
        for (int p=0;p<8;++p) acc[j*8+p] = bb;
    }

    const int ID2=ID*ID;
    const long ID3=(long)ID2*ID;

    for (int ic=0; ic<I; ++ic){
        const float* ip = in + (long)ic*ID3;
        float iv[2][2][2];
        #pragma unroll
        for (int dz=0;dz<2;++dz)
        #pragma unroll
        for (int dy=0;dy<2;++dy)
        #pragma unroll
        for (int dx=0;dx<2;++dx){
            int z = a0-1+dz, y = a1-1+dy, x = a2-1+dx;
            bool ok = (z>=0)&&(y>=0)&&(x>=0);
            iv[dz][dy][dx] = ok ? ip[(long)z*ID2 + y*ID + x] : 0.f;
        }
        #pragma unroll
        for (int j=0;j<OCPB;++j){
            const float* wp = w + ((long)(oc0+j)*I + ic)*27;
            #pragma unroll
            for (int p0=0;p0<2;++p0)
            #pragma unroll
            for (int p1=0;p1<2;++p1)
            #pragma unroll
            for (int p2=0;p2<2;++p2){
                float s = 0.f;
                #pragma unroll
                for (int q0=0;q0<(p0?1:2);++q0){
                    int k0 = p0?1:(q0?2:0); int d0 = p0?1:q0;
                    #pragma unroll
                    for (int q1=0;q1<(p1?1:2);++q1){
                        int k1 = p1?1:(q1?2:0); int d1 = p1?1:q1;
                        #pragma unroll
                        for (int q2=0;q2<(p2?1:2);++q2){
                            int k2 = p2?1:(q2?2:0); int d2 = p2?1:q2;
                            s += wp[k0*9+k1*3+k2] * iv[d0][d1][d2];
                        }
                    }
                }
                acc[j*8 + p0*4+p1*2+p2] += s;
            }
        }
    }
    const int OD2 = OD*OD;
    const long OD3 = (long)OD2*OD;
    #pragma unroll
    for (int j=0;j<OCPB;++j)
    #pragma unroll
    for (int p0=0;p0<2;++p0)
    #pragma unroll
    for (int p1=0;p1<2;++p1)
    #pragma unroll
    for (int p2=0;p2<2;++p2){
        out[(long)(oc0+j)*OD3 + (long)(2*a0+p0)*OD2 + (2*a1+p1)*OD + (2*a2+p2)]
            = lrelu_f(acc[j*8 + p0*4+p1*2+p2]);
    }
}

// ---------------- affine head ----------------
static __device__ void mat4mul(const double* A, const double* B, double* C){
    for (int i=0;i<4;++i) for (int j=0;j<4;++j){
        double s=0; for (int k=0;k<4;++k) s += A[i*4+k]*B[k*4+j];
        C[i*4+j]=s;
    }
}

__global__ void affine_k(const float* __restrict__ c4, float* __restrict__ aff_out, float* __restrict__ mats){
    __shared__ float p[7];
    int t = threadIdx.x;
    if (t < 7){
        float s = 0.f;
        for (int i=0;i<N6;++i) s += c4[t*N6 + i];
        p[t] = s / (float)N6;
        aff_out[t] = p[t];
    }
    __syncthreads();
    if (t == 0){
        double M[16];
        for (int i=0;i<16;++i) M[i]=0.0;
        M[0*4+3]=p[0]; M[1*4+3]=p[1]; M[2*4+3]=p[2];
        M[0*4+1]= p[3]; M[1*4+0]=-p[3];
        M[0*4+2]= p[4]; M[2*4+0]=-p[4];
        M[1*4+2]= p[5]; M[2*4+1]=-p[5];
        M[0*4+0]+=p[6]; M[1*4+1]+=p[6]; M[2*4+2]+=p[6];
        double nrm=0.0;
        for (int i=0;i<4;++i){
            double s=0; for (int j=0;j<4;++j) s += fabs(M[i*4+j]);
            if (s>nrm) nrm=s;
        }
        int jj=0;
        while (nrm > 0.25 && jj < 40){ nrm *= 0.5; ++jj; }
        double sc = 1.0; for (int q=0;q<jj;++q) sc *= 0.5;
        double Ms[16]; for (int i=0;i<16;++i) Ms[i]=M[i]*sc;
        double E[16], T[16], Tn[16];
        for (int i=0;i<16;++i){ E[i] = (i%5==0)?1.0:0.0; T[i]=E[i]; }
        for (int k=1;k<=18;++k){
            mat4mul(T, Ms, Tn);
            double inv = 1.0/(double)k;
            for (int i=0;i<16;++i){ T[i]=Tn[i]*inv; E[i]+=T[i]; }
        }
        for (int q=0;q<jj;++q){ mat4mul(E,E,Tn); for (int i=0;i<16;++i) E[i]=Tn[i]; }
        const double tsh = -48.0;
        for (int i=0;i<3;++i){
            for (int j=0;j<3;++j) mats[i*3+j] = (float)E[i*4+j];
            double rs = (E[i*4+0] - (i==0?1.0:0.0))
                      + (E[i*4+1] - (i==1?1.0:0.0))
                      + (E[i*4+2] - (i==2?1.0:0.0));
            mats[9+i] = (float)(E[i*4+3] + rs*tsh);
        }
    }
}

// ---------------- trilinear helpers ----------------
static __device__ __forceinline__ void trilerp3(const float* __restrict__ f, int D,
                                                float c0, float c1, float c2, float out3[3]){
    float f0=floorf(c0), f1=floorf(c1), f2=floorf(c2);
    float w0=c0-f0, w1=c1-f1, w2=c2-f2;
    int a0=(int)f0, a1=(int)f1, a2=(int)f2;
    int i0s[2]={clampi(a0,0,D-1), clampi(a0+1,0,D-1)};
    int i1s[2]={clampi(a1,0,D-1), clampi(a1+1,0,D-1)};
    int i2s[2]={clampi(a2,0,D-1), clampi(a2+1,0,D-1)};
    float w0s[2]={1.f-w0,w0}, w1s[2]={1.f-w1,w1}, w2s[2]={1.f-w2,w2};
    out3[0]=out3[1]=out3[2]=0.f;
    #pragma unroll
    for (int dx=0;dx<2;++dx)
    #pragma unroll
    for (int dy=0;dy<2;++dy)
    #pragma unroll
    for (int dz=0;dz<2;++dz){
        float wg = w0s[dx]*w1s[dy]*w2s[dz];
        const float* pp = f + ((i0s[dx]*D + i1s[dy])*D + i2s[dz])*3;
        out3[0]+=wg*pp[0]; out3[1]+=wg*pp[1]; out3[2]+=wg*pp[2];
    }
}

static __device__ __forceinline__ float trilerp1(const float* __restrict__ f, int D,
                                                 float c0, float c1, float c2){
    float f0=floorf(c0), f1=floorf(c1), f2=floorf(c2);
    float w0=c0-f0, w1=c1-f1, w2=c2-f2;
    int a0=(int)f0, a1=(int)f1, a2=(int)f2;
    int i0s[2]={clampi(a0,0,D-1), clampi(a0+1,0,D-1)};
    int i1s[2]={clampi(a1,0,D-1), clampi(a1+1,0,D-1)};
    int i2s[2]={clampi(a2,0,D-1), clampi(a2+1,0,D-1)};
    float w0s[2]={1.f-w0,w0}, w1s[2]={1.f-w1,w1}, w2s[2]={1.f-w2,w2};
    float s=0.f;
    #pragma unroll
    for (int dx=0;dx<2;++dx)
    #pragma unroll
    for (int dy=0;dy<2;++dy)
    #pragma unroll
    for (int dz=0;dz<2;++dz){
        float wg = w0s[dx]*w1s[dy]*w2s[dz];
        s += wg * f[(i0s[dx]*D + i1s[dy])*D + i2s[dz]];
    }
    return s;
}

// ---------------- vel -> d0 ----------------
__global__ void resize_small_k(const float* __restrict__ vel, float* __restrict__ dA){
    int t = blockIdx.x*blockDim.x + threadIdx.x;
    if (t >= N48) return;
    int i2 = t % 48; int r = t / 48; int i1 = r % 48; int i0 = r / 48;
    const float s = 95.f/47.f;
    float o[3];
    trilerp3(vel, 96, i0*s, i1*s, i2*s, o);
    const float k = 0.5f/256.f;
    dA[t*3+0]=o[0]*k; dA[t*3+1]=o[1]*k; dA[t*3+2]=o[2]*k;
}

// ---------------- squaring iteration ----------------
__global__ void sq_k(const float* __restrict__ din, float* __restrict__ dout){
    int t = blockIdx.x*blockDim.x + threadIdx.x;
    if (t >= N48) return;
    int i2 = t % 48; int r = t / 48; int i1 = r % 48; int i0 = r / 48;
    float d0=din[t*3+0], d1=din[t*3+1], d2=din[t*3+2];
    float s[3];
    trilerp3(din, 48, (float)i0+d0, (float)i1+d1, (float)i2+d2, s);
    dout[t*3+0]=d0+s[0]; dout[t*3+1]=d1+s[1]; dout[t*3+2]=d2+s[2];
}

// ---------------- fused grid upsample + affine + final pull ----------------
__global__ void grid_pull_k(const float* __restrict__ dfin, const float* __restrict__ src,
                            const float* __restrict__ mats, float* __restrict__ out){
    int t = blockIdx.x*blockDim.x + threadIdx.x;
    if (t >= N96) return;
    int i2 = t % 96; int r = t / 96; int i1 = r % 96; int i0 = r / 96;
    const float sc = 47.f/95.f;
    float c0=i0*sc, c1=i1*sc, c2=i2*sc;
    float s[3];
    trilerp3(dfin, 48, c0, c1, c2, s);
    float g0 = 2.f*(c0+s[0]), g1 = 2.f*(c1+s[1]), g2 = 2.f*(c2+s[2]);
    float L00=mats[0],L01=mats[1],L02=mats[2],L10=mats[3],L11=mats[4],L12=mats[5],
          L20=mats[6],L21=mats[7],L22=mats[8],o0=mats[9],o1=mats[10],o2=mats[11];
    float gg0 = L00*g0 + L01*g1 + L02*g2 + o0;
    float gg1 = L10*g0 + L11*g1 + L12*g2 + o1;
    float gg2 = L20*g0 + L21*g1 + L22*g2 + o2;
    bool inb = (gg0>=0.f)&&(gg0<=95.f)&&(gg1>=0.f)&&(gg1<=95.f)&&(gg2>=0.f)&&(gg2<=95.f);
    float val = trilerp1(src, 96, gg0, gg1, gg2);
    out[t] = inb ? val : 0.f;
}

// ---------------- host side ----------------
extern "C" void kernel_launch(void* const* d_in, const int* in_sizes, int n_in,
                              void* d_out, int out_size, void* d_ws, size_t ws_size,
                              hipStream_t stream) {
    const float* src = (const float*)d_in[0];
    const float* tgt = (const float*)d_in[1];
    const float *cw[5], *cb[5], *ew[4], *eb[4], *uw[4], *ub[4], *dw[4], *db[4];
    for (int i=0;i<5;++i){ cw[i]=(const float*)d_in[2+2*i]; cb[i]=(const float*)d_in[3+2*i]; }
    for (int i=0;i<4;++i){ ew[i]=(const float*)d_in[12+2*i]; eb[i]=(const float*)d_in[13+2*i]; }
    for (int i=0;i<4;++i){ uw[i]=(const float*)d_in[20+2*i]; ub[i]=(const float*)d_in[21+2*i]; }
    for (int i=0;i<4;++i){ dw[i]=(const float*)d_in[28+2*i]; db[i]=(const float*)d_in[29+2*i]; }
    const float* fw = (const float*)d_in[36];
    const float* fb = (const float*)d_in[37];

    float* ws = (float*)d_ws;
    const long OFF_X  = 0;
    const long OFF_E0 = OFF_X  + 2L*N96;
    const long OFF_E1 = OFF_E0 + 16L*N48;
    const long OFF_E2 = OFF_E1 + 32L*N24;
    const long OFF_E3 = OFF_E2 + 32L*N12;
    const long OFF_B1 = OFF_E3 + 32L*N6;
    const long OFF_B2 = OFF_B1 + 16L*N96;
    const long OFF_DA = OFF_B2 + 16L*N96;
    const long OFF_DB = OFF_DA + 3L*N48;
    const long OFF_MT = OFF_DB + 3L*N48;
    const long WS_TOT = OFF_MT + 16;
    if (ws_size < (size_t)WS_TOT*4) return;

    float* X  = ws + OFF_X;
    float* E0 = ws + OFF_E0;
    float* E1 = ws + OFF_E1;
    float* E2 = ws + OFF_E2;
    float* E3 = ws + OFF_E3;
    float* B1 = ws + OFF_B1;
    float* B2 = ws + OFF_B2;
    float* DA = ws + OFF_DA;
    float* DB = ws + OFF_DB;
    float* MT = ws + OFF_MT;

    float* out_def = (float*)d_out;
    float* out_vel = out_def + N96;
    float* out_aff = out_vel + 3L*N96;

    auto gsz = [](int n, int b){ return (n + b - 1)/b; };

    concat_k<<<gsz(N96,256), 256, 0, stream>>>(src, tgt, X);

    // fused cnn/enc downsample cascade: z=0 -> cnn path (B1/B2 ping-pong), z=1 -> enc path (E0..E3)
    conv3d_dual_k< 8,2,true><<<dim3(gsz(N48,256), 2,2), 256, 0, stream>>>(src,tgt, src,tgt, 1,1, cw[0],cb[0], ew[0],eb[0], B1,E0, 96,48);
    conv3d_dual_k< 4,2,true><<<dim3(gsz(N24,256), 8,2), 256, 0, stream>>>(B1,nullptr, E0,nullptr, 16,0, cw[1],cb[1], ew[1],eb[1], B2,E1, 48,24);
    conv3d_dual_k< 2,2,true><<<dim3(gsz(N12, 64),16,2),  64, 0, stream>>>(B2,nullptr, E1,nullptr, 32,0, cw[2],cb[2], ew[2],eb[2], B1,E2, 24,12);
    conv3d_dual_k< 1,2,true><<<dim3(gsz(N6 , 64),32,2),  64, 0, stream>>>(B1,nullptr, E2,nullptr, 32,0, cw[3],cb[3], ew[3],eb[3], B2,E3, 12, 6);
    conv3d_k< 1,1,false><<<dim3(gsz(N6 , 64), 7), 64, 0, stream>>>(B2,32, nullptr, 0, cw[4], cb[4], B1, 6, 6, N6, 1);
    affine_k<<<1, 64, 0, stream>>>(B1, out_aff, MT);

    // decoder
    convt_cell_k<1><<<dim3(gsz(N6 , 64),32), 64, 0, stream>>>(E3, 32, uw[0], ub[0], B2, 6);
    conv3d_k< 2,1,true><<<dim3(gsz(N12, 64),16), 64, 0, stream>>>(B2,32, E2,32, dw[0], db[0], B1, 12, 12, N12, 1);
    convt_cell_k<4><<<dim3(gsz(N12, 64), 8), 64, 0, stream>>>(B1, 32, uw[1], ub[1], B2, 12);
    conv3d_k< 4,1,true><<<dim3(gsz(N24,256), 8), 256, 0, stream>>>(B2,32, E1,32, dw[1], db[1], B1, 24, 24, N24, 1);
    convt_cell_k<4><<<dim3(gsz(N24,256), 8), 256, 0, stream>>>(B1, 32, uw[2], ub[2], B2, 24);
    conv3d_k< 8,1,true><<<dim3(gsz(N48,256), 4), 256, 0, stream>>>(B2,32, E0,16, dw[2], db[2], B1, 48, 48, N48, 1);
    convt_cell_k<4><<<dim3(gsz(N48,256), 4), 256, 0, stream>>>(B1, 32, uw[3], ub[3], B2, 48);
    conv3d_k< 8,1,true><<<dim3(gsz(N96,256), 2), 256, 0, stream>>>(B2,16, X, 2, dw[3], db[3], B1, 96, 96, N96, 1);

    // final conv -> vel (channel-last into d_out)
    conv3d_k< 3,1,false><<<dim3(gsz(N96,256), 1), 256, 0, stream>>>(B1,16, nullptr, 0, fw, fb, out_vel, 96, 96, 1, 3);

    // velocity integration
    resize_small_k<<<gsz(N48,256), 256, 0, stream>>>(out_vel, DA);
    float* da = DA; float* dbuf = DB;
    for (int it=0; it<8; ++it){
        sq_k<<<gsz(N48,256), 256, 0, stream>>>(da, dbuf);
        float* tmp = da; da = dbuf; dbuf = tmp;
    }

    // grid upsample + affine + final warp
    grid_pull_k<<<gsz(N96,256), 256, 0, stream>>>(da, src, MT, out_def);
}